// Round 2
// baseline (11862.222 us; speedup 1.0000x reference)
//
#include <hip/hip_runtime.h>

// SlowRNN: out[t] = h_{t+1} = tanh(x_t @ Wxh^T + bh + h_t @ Whh^T), h_0 = 0
// T=512, B=64, IN=H=1024.  fp32 in / fp32 out, threshold 2e-2 -> fp16 MFMA compute.
//
// Design: ONE persistent kernel, 256 wgs (1/CU), 256 thr (4 waves).
//  - 16 clusters x 16 wgs. Cluster c owns batches 4c..4c+3; wg member owns 64 feats
//    (16/wave). Cluster wgs share an XCD via blockIdx swizzle (bidx&7 -> XCD).
//  - Wxh and Whh slices live in VGPRs as fp16 MFMA B-fragments (64 x f16x8 = 256 regs)
//    -> zero weight traffic per step; xproj GEMM fused into the step.
//  - Per step: stage h_t (agent-scope atomic b64 loads, L1/L2-bypass) -> LDS;
//    x_t already in LDS (double-buffered, prefetched); 32 x-MFMAs overlap the h loads;
//    32 h-MFMAs; epilogue tanh (lanes 0-15 hold all valid C rows: row=4*(l>>4)+reg);
//    store h_{t+1} fp16 + fp32 out; __threadfence; per-cluster atomic barrier.
//  - MFMA layout: A m=lane&15, B n=lane&15, k = (lane>>4)*8+j for BOTH A and B
//    (shared k-bijection => result invariant to the HW's true k-order).
//    C/D: col=lane&15, row=(lane>>4)*4+reg  [HW-verified].
// ws: hglob fp16[2][64][1024] @0 (256KB), flags u32 @262144 (16 clusters * 64B).

typedef _Float16 f16;
typedef _Float16 f16x8 __attribute__((ext_vector_type(8)));
typedef float f32x4 __attribute__((ext_vector_type(4)));

#define T_STEPS 512
#define NB 64
#define NH 1024
#define ROWP 1040  // padded LDS row (elems): 2080B stride -> 2-way-max bank pattern

__device__ __forceinline__ f16x8 cvt8(const float4 a, const float4 b) {
    f16x8 v;
    v[0] = (f16)a.x; v[1] = (f16)a.y; v[2] = (f16)a.z; v[3] = (f16)a.w;
    v[4] = (f16)b.x; v[5] = (f16)b.y; v[6] = (f16)b.z; v[7] = (f16)b.w;
    return v;
}

extern "C" __global__ void __launch_bounds__(256, 1)
rnn_persist(const float* __restrict__ x, const float* __restrict__ Wxh,
            const float* __restrict__ Whh, const float* __restrict__ bh,
            float* __restrict__ out, f16* __restrict__ hglob,
            unsigned int* __restrict__ flags)
{
    __shared__ __align__(16) f16 xlds[2][4 * ROWP];
    __shared__ __align__(16) f16 hlds[4 * ROWP];

    const int tid  = threadIdx.x;
    const int lane = tid & 63;
    const int wv   = tid >> 6;
    const int g    = (lane >> 4) & 3;   // k-group within wave
    const int l15  = lane & 15;

    const int bidx    = blockIdx.x;
    // cluster = same low-3 bits (same XCD under round-robin) + bit3; member = high bits
    const int cluster = ((bidx & 7) << 1) | ((bidx >> 3) & 1);
    const int member  = bidx >> 4;
    const int bbase   = cluster * 4;                 // 4 batches per cluster
    const int n       = member * 64 + wv * 16 + l15; // feature this lane owns

    // ---- preload weight fragments into VGPRs (fp16) ----
    // B-frag[k][n]: value = W[n][k], k = kt*32 + g*8 + j  (contiguous along W's row)
    f16x8 bx[32], bw[32];
#pragma unroll
    for (int kt = 0; kt < 32; ++kt) {
        const float* px = Wxh + (size_t)n * NH + kt * 32 + g * 8;
        const float* pw = Whh + (size_t)n * NH + kt * 32 + g * 8;
        float4 a0 = ((const float4*)px)[0], a1 = ((const float4*)px)[1];
        float4 c0 = ((const float4*)pw)[0], c1 = ((const float4*)pw)[1];
        bx[kt] = cvt8(a0, a1);
        bw[kt] = cvt8(c0, c1);
    }
    const float bias = bh[n];

    // ---- staging geometry: thread stages 32B of batch row sb at k-offset sk ----
    const int sb = tid >> 6;           // 0..3 (wave stages one batch row)
    const int sk = (tid & 63) * 16;    // 16 elems per thread
    const float* xsrc0 = x + ((size_t)(bbase + sb)) * NH + sk;
    f16* xd0 = &xlds[0][sb * ROWP + sk];
    f16* xd1 = &xlds[1][sb * ROWP + sk];
    f16* hdst = &hlds[sb * ROWP + sk];

    const f16* xa0 = &xlds[0][(l15 & 3) * ROWP + g * 8]; // A-frag base (b = m&3 clamp)
    const f16* xa1 = &xlds[1][(l15 & 3) * ROWP + g * 8];
    const f16* ha  = &hlds[(l15 & 3) * ROWP + g * 8];

    float4 xr0, xr1, xr2, xr3;                         // x prefetch regs
    unsigned long long hv0, hv1, hv2, hv3;             // h stage regs
    const unsigned long long* hbase = (const unsigned long long*)hglob;

    f32x4 acc[8];

    auto load_x = [&](int t) {
        const float4* p = (const float4*)(xsrc0 + (size_t)t * (NB * NH));
        xr0 = p[0]; xr1 = p[1]; xr2 = p[2]; xr3 = p[3];
    };
    auto write_x = [&](int par) {
        f16* d = par ? xd1 : xd0;
        *(f16x8*)d       = cvt8(xr0, xr1);
        *(f16x8*)(d + 8) = cvt8(xr2, xr3);
    };
    auto stage_h_load = [&](int par) {  // agent-scope: bypass stale L1/L2
        const unsigned long long* s =
            hbase + ((size_t)(par * NB + bbase + sb)) * (NH / 4) + (size_t)(tid & 63) * 4;
        hv0 = __hip_atomic_load(s + 0, __ATOMIC_RELAXED, __HIP_MEMORY_SCOPE_AGENT);
        hv1 = __hip_atomic_load(s + 1, __ATOMIC_RELAXED, __HIP_MEMORY_SCOPE_AGENT);
        hv2 = __hip_atomic_load(s + 2, __ATOMIC_RELAXED, __HIP_MEMORY_SCOPE_AGENT);
        hv3 = __hip_atomic_load(s + 3, __ATOMIC_RELAXED, __HIP_MEMORY_SCOPE_AGENT);
    };
    auto stage_h_write = [&]() {
        *(unsigned long long*)(hdst + 0)  = hv0;
        *(unsigned long long*)(hdst + 4)  = hv1;
        *(unsigned long long*)(hdst + 8)  = hv2;
        *(unsigned long long*)(hdst + 12) = hv3;
    };
    auto zero_acc = [&]() {
#pragma unroll
        for (int i = 0; i < 8; ++i) acc[i] = f32x4{0.f, 0.f, 0.f, 0.f};
    };
    auto mfma_x = [&](const f16* xa) {
#pragma unroll
        for (int kt = 0; kt < 32; ++kt)
            acc[kt & 7] = __builtin_amdgcn_mfma_f32_16x16x32_f16(
                *(const f16x8*)(xa + kt * 32), bx[kt], acc[kt & 7], 0, 0, 0);
    };
    auto mfma_h = [&]() {
#pragma unroll
        for (int kt = 0; kt < 32; ++kt)
            acc[(kt + 4) & 7] = __builtin_amdgcn_mfma_f32_16x16x32_f16(
                *(const f16x8*)(ha + kt * 32), bw[kt], acc[(kt + 4) & 7], 0, 0, 0);
    };
    auto epilogue = [&](int t) {
        f32x4 s = ((acc[0] + acc[1]) + (acc[2] + acc[3])) +
                  ((acc[4] + acc[5]) + (acc[6] + acc[7]));
        if (lane < 16) {  // C/D rows 0..3 live in lanes 0-15, regs 0-3
            const int par = (t + 1) & 1;
#pragma unroll
            for (int r = 0; r < 4; ++r) {
                const int b = bbase + r;
                float pre = s[r] + bias;
                float hv  = tanhf(pre);
                __builtin_nontemporal_store(hv, out + ((size_t)t * NB + b) * NH + n);
                hglob[((size_t)par * NB + b) * NH + n] = (f16)hv;
                if (t == T_STEPS - 1)
                    __builtin_nontemporal_store(
                        hv, out + (size_t)T_STEPS * NB * NH + (size_t)b * NH + n);
            }
        }
    };
    unsigned int* flagp = flags + cluster * 16;  // 64B stride per cluster
    auto barrier_step = [&](int t) {
        __syncthreads();  // all threads' fences/stores done before arrive
        if (tid == 0) {
            __hip_atomic_fetch_add(flagp, 1u, __ATOMIC_RELEASE, __HIP_MEMORY_SCOPE_AGENT);
            const unsigned int target = 16u * (unsigned)(t + 1);
            int guard = 1 << 20;  // no-hang safety: wrong-but-terminating on deadlock
            while (__hip_atomic_load(flagp, __ATOMIC_ACQUIRE, __HIP_MEMORY_SCOPE_AGENT) <
                       target && --guard)
                __builtin_amdgcn_s_sleep(1);
        }
        __syncthreads();
    };

    // ---- t = 0: h_0 = 0, x-products only ----
    load_x(0); write_x(0);
    load_x(1);                    // prefetch x_1
    __syncthreads();              // xlds[0] ready
    zero_acc();
    mfma_x(xa0);
    epilogue(0);
    __threadfence();              // h_1 visible device-wide
    write_x(1);                   // xlds[1] (untouched by anyone this step)
    barrier_step(0);

    // ---- main loop ----
    for (int t = 1; t < T_STEPS; ++t) {
        const int par = t & 1;
        stage_h_load(par);                    // issue h loads (latency hidden below)
        zero_acc();
        mfma_x(par ? xa1 : xa0);              // x-half while h loads fly
        stage_h_write();                      // (waitcnt inserted by compiler)
        if (t < T_STEPS - 1) load_x(t + 1);   // prefetch next x to regs
        __syncthreads();                      // hlds ready for all waves
        mfma_h();
        epilogue(t);
        if (t < T_STEPS - 1) {
            __threadfence();
            write_x((t + 1) & 1);
            barrier_step(t);
        }
    }
}

extern "C" void kernel_launch(void* const* d_in, const int* in_sizes, int n_in,
                              void* d_out, int out_size, void* d_ws, size_t ws_size,
                              hipStream_t stream) {
    const float* x   = (const float*)d_in[0];
    const float* Wxh = (const float*)d_in[1];
    const float* Whh = (const float*)d_in[2];
    const float* bh  = (const float*)d_in[3];
    float* out       = (float*)d_out;
    f16* hglob       = (f16*)d_ws;                              // 256 KB
    unsigned int* flags = (unsigned int*)((char*)d_ws + 262144); // 16 x 64B
    hipMemsetAsync(flags, 0, 16 * 64, stream);                   // barrier counters = 0
    rnn_persist<<<dim3(256), dim3(256), 0, stream>>>(x, Wxh, Whh, bh, out, hglob, flags);
}

// Round 3
// 2323.530 us; speedup vs baseline: 5.1053x; 5.1053x over previous
//
#include <hip/hip_runtime.h>

// SlowRNN: out[t] = h_{t+1} = tanh(x_t @ Wxh^T + bh + h_t @ Whh^T), h_0 = 0
// T=512, B=64, IN=H=1024.  fp32 in / fp32 out, threshold 2e-2 -> fp16 MFMA compute.
//
// v2: same geometry as v1 (16 clusters x 16 wgs, weights VGPR-resident, fused xproj),
// sync rebuilt around RELAXED agent-scope (sc1, cache-bypass) accesses ONLY:
//  - h exchanged as fp32 via relaxed agent atomic stores/loads (straight to MALL;
//    no L1/L2 staleness possible since h is *only ever* touched at agent scope).
//  - ordering: h-stores -> s_waitcnt vmcnt(0) -> per-member flag store (relaxed).
//    NO __threadfence (no buffer_wbl2), NO acquire polls (no buffer_inv per iter).
//  - barrier: 16 per-member flag words (64B apart); all lanes poll coalesced-ish,
//    __all() over the wave; no atomic RMW contention.
//  - out nt-stores issued AFTER the vmcnt so HBM store-ack is off the critical path.
//  - tanh via __expf: 1 - 2/(e^{2x}+1)  (~10 inst vs tanhf's ~30).
// WAR safety: own-wg flag(t) implies all own waves passed the pre-flag
// __syncthreads of step t-1, which orders all LDS writes/reads across steps.
// ws: hglob f32[2][64][1024] @0 (512KB); flags @524288: 16 cl x 16 mem x 64B (16KB).

typedef _Float16 f16;
typedef _Float16 f16x8 __attribute__((ext_vector_type(8)));
typedef float f32x4 __attribute__((ext_vector_type(4)));
typedef unsigned int u32;
typedef unsigned long long u64;

#define T_STEPS 512
#define NB 64
#define NH 1024
#define ROWP 1040  // padded LDS row (f16 elems), 2080B stride

__device__ __forceinline__ f16x8 cvt8(const float4 a, const float4 b) {
    f16x8 v;
    v[0] = (f16)a.x; v[1] = (f16)a.y; v[2] = (f16)a.z; v[3] = (f16)a.w;
    v[4] = (f16)b.x; v[5] = (f16)b.y; v[6] = (f16)b.z; v[7] = (f16)b.w;
    return v;
}

__device__ __forceinline__ float fast_tanh(float x) {
    // 1 - 2/(e^{2x}+1); e=inf -> 1, e=0 -> -1. err ~1e-6 << fp16 noise.
    float e = __expf(2.0f * x);
    return 1.0f - 2.0f / (e + 1.0f);
}

extern "C" __global__ void __launch_bounds__(256, 1)
rnn_persist(const float* __restrict__ x, const float* __restrict__ Wxh,
            const float* __restrict__ Whh, const float* __restrict__ bh,
            float* __restrict__ out, float* __restrict__ hglob,
            u32* __restrict__ flags)
{
    __shared__ __align__(16) f16 xlds[2][4 * ROWP];
    __shared__ __align__(16) f16 hlds[4 * ROWP];

    const int tid  = threadIdx.x;
    const int lane = tid & 63;
    const int wv   = tid >> 6;
    const int g    = (lane >> 4) & 3;   // k-group within wave
    const int l15  = lane & 15;

    const int bidx    = blockIdx.x;
    const int cluster = ((bidx & 7) << 1) | ((bidx >> 3) & 1);  // perf-only XCD grouping
    const int member  = bidx >> 4;
    const int bbase   = cluster * 4;                 // 4 batches per cluster
    const int n       = member * 64 + wv * 16 + l15; // feature this lane owns

    // ---- weight fragments resident in VGPRs (fp16) ----
    f16x8 bx[32], bw[32];
#pragma unroll
    for (int kt = 0; kt < 32; ++kt) {
        const float* px = Wxh + (size_t)n * NH + kt * 32 + g * 8;
        const float* pw = Whh + (size_t)n * NH + kt * 32 + g * 8;
        float4 a0 = ((const float4*)px)[0], a1 = ((const float4*)px)[1];
        float4 c0 = ((const float4*)pw)[0], c1 = ((const float4*)pw)[1];
        bx[kt] = cvt8(a0, a1);
        bw[kt] = cvt8(c0, c1);
    }
    const float bias = bh[n];

    // ---- staging geometry ----
    const int sb = wv;                 // wave stages one batch row
    const float* xsrc0 = x + (size_t)(bbase + sb) * NH + lane * 16;
    f16* xd0  = &xlds[0][sb * ROWP + lane * 16];
    f16* xd1  = &xlds[1][sb * ROWP + lane * 16];
    f16* hdst = &hlds[sb * ROWP + lane * 16];

    const f16* xa0 = &xlds[0][(l15 & 3) * ROWP + g * 8];
    const f16* xa1 = &xlds[1][(l15 & 3) * ROWP + g * 8];
    const f16* ha  = &hlds[(l15 & 3) * ROWP + g * 8];

    float4 xr0, xr1, xr2, xr3;
    u64 hv[8];                                        // 16 f32 of h per lane
    const u64* hb = (const u64*)hglob;
    u32* hgu = (u32*)hglob;

    f32x4 acc[8];
    float hvv[4];

    auto load_x = [&](int t) {
        const float4* p = (const float4*)(xsrc0 + (size_t)t * (NB * NH));
        xr0 = p[0]; xr1 = p[1]; xr2 = p[2]; xr3 = p[3];
    };
    auto write_x = [&](int par) {
        f16* d = par ? xd1 : xd0;
        *(f16x8*)d       = cvt8(xr0, xr1);
        *(f16x8*)(d + 8) = cvt8(xr2, xr3);
    };
    auto stage_h_load = [&](int par) {  // relaxed agent (sc1): reads coherence point
        const u64* s = hb + ((size_t)(par * NB + bbase + sb)) * (NH / 2) + (size_t)lane * 8;
#pragma unroll
        for (int i = 0; i < 8; ++i)
            hv[i] = __hip_atomic_load(s + i, __ATOMIC_RELAXED, __HIP_MEMORY_SCOPE_AGENT);
    };
    auto stage_h_write = [&]() {
        f16x8 lo, hi;
#pragma unroll
        for (int i = 0; i < 4; ++i) {
            float2 p0 = __builtin_bit_cast(float2, hv[i]);
            float2 p1 = __builtin_bit_cast(float2, hv[4 + i]);
            lo[2 * i] = (f16)p0.x; lo[2 * i + 1] = (f16)p0.y;
            hi[2 * i] = (f16)p1.x; hi[2 * i + 1] = (f16)p1.y;
        }
        *(f16x8*)hdst       = lo;
        *(f16x8*)(hdst + 8) = hi;
    };
    auto zero_acc = [&]() {
#pragma unroll
        for (int i = 0; i < 8; ++i) acc[i] = f32x4{0.f, 0.f, 0.f, 0.f};
    };
    auto mfma_x = [&](const f16* xa) {
#pragma unroll
        for (int kt = 0; kt < 32; ++kt)
            acc[kt & 7] = __builtin_amdgcn_mfma_f32_16x16x32_f16(
                *(const f16x8*)(xa + kt * 32), bx[kt], acc[kt & 7], 0, 0, 0);
    };
    auto mfma_h = [&]() {
#pragma unroll
        for (int kt = 0; kt < 32; ++kt)
            acc[(kt + 4) & 7] = __builtin_amdgcn_mfma_f32_16x16x32_f16(
                *(const f16x8*)(ha + kt * 32), bw[kt], acc[(kt + 4) & 7], 0, 0, 0);
    };
    // compute h_{t+1} and push it to the coherence point (relaxed sc1 stores only)
    auto compute_h = [&](int t) {
        f32x4 s = ((acc[0] + acc[1]) + (acc[2] + acc[3])) +
                  ((acc[4] + acc[5]) + (acc[6] + acc[7]));
        if (lane < 16) {
            const int par = (t + 1) & 1;
#pragma unroll
            for (int r = 0; r < 4; ++r) {
                hvv[r] = fast_tanh(s[r] + bias);
                const size_t idx = ((size_t)par * NB + bbase + r) * NH + n;
                __hip_atomic_store(hgu + idx, __builtin_bit_cast(u32, hvv[r]),
                                   __ATOMIC_RELAXED, __HIP_MEMORY_SCOPE_AGENT);
            }
        }
    };
    auto out_stores = [&](int t) {  // off the protocol critical path
        if (lane < 16) {
#pragma unroll
            for (int r = 0; r < 4; ++r) {
                const int b = bbase + r;
                __builtin_nontemporal_store(hvv[r], out + ((size_t)t * NB + b) * NH + n);
                if (t == T_STEPS - 1)
                    __builtin_nontemporal_store(
                        hvv[r], out + (size_t)T_STEPS * NB * NH + (size_t)b * NH + n);
            }
        }
    };
    u32* flagp = flags + cluster * 256 + member * 16;      // 64B member stride
    const u32* fpoll = flags + cluster * 256 + l15 * 16;   // lane l polls member l&15
    auto poll = [&](u32 target) {
        int guard = 1 << 16;  // hang-safety: wrong-but-terminating on deadlock
        for (;;) {
            u32 v = __hip_atomic_load(fpoll, __ATOMIC_RELAXED, __HIP_MEMORY_SCOPE_AGENT);
            if (__all((int)(v >= target))) break;
            if (--guard == 0) break;
            __builtin_amdgcn_s_sleep(1);
        }
        asm volatile("" ::: "memory");
    };

    // ---- t = 0: h_0 = 0 ----
    load_x(0); write_x(0);
    load_x(1);
    __syncthreads();
    zero_acc();
    mfma_x(xa0);
    compute_h(0);
    asm volatile("s_waitcnt vmcnt(0)" ::: "memory");  // h-stores acked at MALL
    write_x(1);
    __syncthreads();                                  // all waves' h acked + LDS staged
    if (tid == 0)
        __hip_atomic_store(flagp, 1u, __ATOMIC_RELAXED, __HIP_MEMORY_SCOPE_AGENT);
    out_stores(0);
    poll(1);

    // ---- main loop ----
    for (int t = 1; t < T_STEPS; ++t) {
        const int par = t & 1;
        stage_h_load(par);                    // issue sc1 loads; latency under mfma_x
        zero_acc();
        mfma_x(par ? xa1 : xa0);
        stage_h_write();                      // waits hv, cvt fp32->fp16, LDS
        if (t < T_STEPS - 1) load_x(t + 1);
        __syncthreads();                      // hlds ready for all waves
        mfma_h();
        compute_h(t);
        asm volatile("s_waitcnt vmcnt(0)" ::: "memory");
        if (t < T_STEPS - 1) write_x((t + 1) & 1);
        __syncthreads();
        if (t < T_STEPS - 1) {
            if (tid == 0)
                __hip_atomic_store(flagp, (u32)(t + 1), __ATOMIC_RELAXED,
                                   __HIP_MEMORY_SCOPE_AGENT);
            out_stores(t);
            poll((u32)(t + 1));
        } else {
            out_stores(t);
        }
    }
}

extern "C" void kernel_launch(void* const* d_in, const int* in_sizes, int n_in,
                              void* d_out, int out_size, void* d_ws, size_t ws_size,
                              hipStream_t stream) {
    const float* x   = (const float*)d_in[0];
    const float* Wxh = (const float*)d_in[1];
    const float* Whh = (const float*)d_in[2];
    const float* bh  = (const float*)d_in[3];
    float* out       = (float*)d_out;
    float* hglob     = (float*)d_ws;                          // 512 KB fp32 h x2
    u32* flags       = (u32*)((char*)d_ws + 524288);          // 16 KB
    hipMemsetAsync(flags, 0, 16 * 16 * 64, stream);
    rnn_persist<<<dim3(256), dim3(256), 0, stream>>>(x, Wxh, Whh, bh, out, hglob, flags);
}